// Round 15
// baseline (504.897 us; speedup 1.0000x reference)
//
#include <hip/hip_runtime.h>
#include <hip/hip_bf16.h>
#include <cstdio>
#include <cstdint>

#define B_    2
#define S_    2048
#define H_    32
#define KVH_  8
#define D_    128
#define HID_  4096
#define WIN_  512
#define NROW_ (B_*S_)          // 4096 rows for projection GEMMs
#define NKV_  2048             // fused k|v output width
#define SCALE_ 0.08838834764831845f          // 128^-0.5
#define SL2E_  0.12751744932973953f          // SCALE_ * log2(e)

typedef __attribute__((ext_vector_type(8))) __bf16 bf16x8;
typedef __attribute__((ext_vector_type(4))) __bf16 bf16x4;
typedef __attribute__((ext_vector_type(4))) float  f32x4;

#define GAS __attribute__((address_space(1)))
#define LAS __attribute__((address_space(3)))

// ------------------------------------------------- merged prep: cvt hidden + 4 weight transposes
__global__ __launch_bounds__(256) void prep_all(const float* __restrict__ hidden,
                                                const float* __restrict__ wq,
                                                const float* __restrict__ wk,
                                                const float* __restrict__ wv,
                                                const float* __restrict__ wo,
                                                __hip_bfloat16* __restrict__ hb,
                                                __hip_bfloat16* __restrict__ wqT,
                                                __hip_bfloat16* __restrict__ wkvT,
                                                __hip_bfloat16* __restrict__ woT) {
    __shared__ float t[32][33];
    const int bid = blockIdx.x;
    if (bid < 16384) {
        const int i = (bid * 256 + threadIdx.x) * 4;
        float4 v = *(const float4*)(hidden + i);
        __hip_bfloat162 a, b;
        a.x = __float2bfloat16(v.x); a.y = __float2bfloat16(v.y);
        b.x = __float2bfloat16(v.z); b.y = __float2bfloat16(v.w);
        *(__hip_bfloat162*)(hb + i)     = a;
        *(__hip_bfloat162*)(hb + i + 2) = b;
        return;
    }
    const int tx = threadIdx.x & 31, ty = threadIdx.x >> 5;
    const int id = bid - 16384;
    const float* src; __hip_bfloat16* dst; int C, idx;   // R always 4096
    if (id < 16384)      { src = wq; dst = wqT;  C = 4096; idx = id; }
    else if (id < 20480) { src = wk; dst = wkvT; C = 1024; idx = id - 16384; }
    else if (id < 24576) { src = wv; dst = wkvT + (size_t)1024*HID_; C = 1024; idx = id - 20480; }
    else                 { src = wo; dst = woT;  C = 4096; idx = id - 24576; }
    const int ctiles = C >> 5;
    const int c0 = (idx % ctiles) * 32, r0 = (idx / ctiles) * 32;
    #pragma unroll
    for (int i = 0; i < 4; ++i)
        t[ty + 8*i][tx] = src[(size_t)(r0 + ty + 8*i) * C + c0 + tx];
    __syncthreads();
    #pragma unroll
    for (int i = 0; i < 4; ++i)
        dst[(size_t)(c0 + ty + 8*i) * HID_ + r0 + tx] = __float2bfloat16(t[tx][ty + 8*i]);
}

// ------------------------------------------------- GEMM 128x256, BK=32, ring-3, 2 blocks/CU
// R15: restore cross-block TLP.  BM=128 -> grid 512 = 2 resident blocks/CU (ring-3 LDS
// 72KB, launch_bounds(512,4) caps VGPR 128).  Two blocks' barriers are independent, so one
// block's MFMAs overlap the other's LDS reads / barrier waits (m114 mechanism, m103 data).
// Counted staging: stage tile t+2 during t; trailing vmcnt(3) confirms t+1 (loads 1 tile
// old), leaves t+2's 3 in flight.  WAR: slot (t+2)%3 last read in tile t-1, completed
// before t-1's end barrier which precedes this stage in program order.
template <int OMODE>   // 0: f32 out, 1: bf16 out
__global__ __launch_bounds__(512, 4) void gemm128(const __hip_bfloat16* __restrict__ A,
                                                  const __hip_bfloat16* __restrict__ Bt,
                                                  void* __restrict__ Cv,
                                                  int M, int N, int K, int nbx) {
    constexpr int SLOT = (128 + 256) * 32;              // 12288 elems = 24 KB (A then B)
    __shared__ __align__(16) __hip_bfloat16 L[3 * SLOT];   // 72 KB
    const int tid  = threadIdx.x;
    const int lane = tid & 63, w = tid >> 6;
    const int wm = w >> 2, wn = w & 3;                  // 2 x 4 wave grid; wave C = 64x64
    const int lc = lane & 15, lg = lane >> 4;
    const int nwg = gridDim.x, cpx = nwg >> 3;          // XCD swizzle (nwg % 8 == 0)
    const int bid = blockIdx.x;
    const int swz = (bid & 7) * cpx + (bid >> 3);
    const int by = swz / nbx, bx = swz - by * nbx;
    const size_t row0 = (size_t)by * 128, col0 = (size_t)bx * 256;
    const int nt = K >> 5;                              // BK = 32

    const int srow = tid >> 2;                          // 0..127
    const int spc  = tid & 3;
    const int slx  = spc ^ ((srow >> 1) & 3);           // pre-inverse-swizzled source chunk
    const __hip_bfloat16* Ab = A  + row0 * K;
    const __hip_bfloat16* Bb = Bt + col0 * K;

#define STG(ss_, tile_) do {                                                               \
    const int kt_ = ((tile_) < nt) ? (tile_) : (nt - 1);  /* clamped tail, uniform count */\
    __builtin_amdgcn_global_load_lds(                                                      \
        (const GAS void*)(Ab + (size_t)srow * K + kt_*32 + slx*8),                         \
        (LAS void*)&L[(ss_)*SLOT + w*512], 16, 0, 0);                                      \
    _Pragma("unroll")                                                                      \
    for (int bh_ = 0; bh_ < 2; ++bh_)                                                      \
        __builtin_amdgcn_global_load_lds(                                                  \
            (const GAS void*)(Bb + (size_t)(bh_*128 + srow) * K + kt_*32 + slx*8),         \
            (LAS void*)&L[(ss_)*SLOT + 4096 + bh_*4096 + w*512], 16, 0, 0);                \
} while (0)

    f32x4 acc[4][4] = {};
    bf16x8 afr[4], bfr[4];

    // prologue: stage tiles 0,1 into slots 0,1; confirm tile 0 (6 outstanding -> wait 3)
    STG(0, 0); STG(1, 1);
    asm volatile("s_waitcnt vmcnt(3)" ::: "memory");
    asm volatile("s_barrier" ::: "memory");

    int sl = 0;                                         // slot of tile t
    for (int t = 0; t < nt; ++t) {
        const int st2 = (sl + 2 >= 3) ? (sl - 1) : (sl + 2);   // slot of tile t+2

        // reads of tile t (compiler interleaves its own lgkm waits with MFMAs)
        #pragma unroll
        for (int fm = 0; fm < 4; ++fm) {
            const int rA = wm*64 + fm*16 + lc;
            afr[fm] = *(const bf16x8*)&L[sl*SLOT + rA*32 + ((lg ^ ((rA >> 1) & 3)) * 8)];
        }
        #pragma unroll
        for (int fn = 0; fn < 4; ++fn) {
            const int rB = wn*64 + fn*16 + lc;
            bfr[fn] = *(const bf16x8*)&L[sl*SLOT + 4096 + rB*32 + ((lg ^ ((rB >> 1) & 3)) * 8)];
        }
        STG(st2, t + 2);

        __builtin_amdgcn_s_setprio(1);
        #pragma unroll
        for (int fm = 0; fm < 4; ++fm)
            #pragma unroll
            for (int fn = 0; fn < 4; ++fn)
                acc[fm][fn] = __builtin_amdgcn_mfma_f32_16x16x32_bf16(
                    afr[fm], bfr[fn], acc[fm][fn], 0, 0, 0);
        __builtin_amdgcn_s_setprio(0);

        asm volatile("s_waitcnt vmcnt(3)" ::: "memory");    // confirm t+1; t+2 in flight
        asm volatile("s_barrier" ::: "memory");
        sl = (sl + 1 == 3) ? 0 : sl + 1;
    }
#undef STG
    asm volatile("s_waitcnt vmcnt(0)" ::: "memory");    // drain clamped tail stages

    #pragma unroll
    for (int fm = 0; fm < 4; ++fm)
        #pragma unroll
        for (int fn = 0; fn < 4; ++fn) {
            const size_t col = col0 + wn*64 + fn*16 + lc;
            #pragma unroll
            for (int rr = 0; rr < 4; ++rr) {
                const size_t row = row0 + wm*64 + fm*16 + lg*4 + rr;
                if constexpr (OMODE == 0)
                    ((float*)Cv)[row * N + col] = acc[fm][fn][rr];
                else
                    ((__hip_bfloat16*)Cv)[row * N + col] = __float2bfloat16(acc[fm][fn][rr]);
            }
        }
}

// ------------------------------------------------- GEMM 256xBN, BK=32, ring-4 (KV, R14-proven)
// OMODE 2: KV fused — bx<8: K head-slab LayerNorm+RoPE in-epilogue -> kr; bx>=8: V cols
// transposed via LDS -> vt (B,KVH,D,S).
template <int FN, int OMODE>
__global__ __launch_bounds__(512, 2) void gemm_t(const __hip_bfloat16* __restrict__ A,
                                                 const __hip_bfloat16* __restrict__ Bt,
                                                 void* __restrict__ Cv, void* __restrict__ C2,
                                                 const float* __restrict__ knw,
                                                 const float* __restrict__ cosT,
                                                 const float* __restrict__ sinT,
                                                 const int* __restrict__ pids,
                                                 int M, int N, int K, int nbx) {
    constexpr int BN   = FN * 64;
    constexpr int BLD  = BN / 128;
    constexpr int SLOT = (256 + BN) * 32;
    __shared__ __align__(16) __hip_bfloat16 L[4 * SLOT];
    const int tid  = threadIdx.x;
    const int lane = tid & 63, w = tid >> 6;
    const int wm = w >> 2, wn = w & 3;
    const int lc = lane & 15, lg = lane >> 4;
    const int nwg = gridDim.x, cpx = nwg >> 3;
    const int bid = blockIdx.x;
    const int swz = (bid & 7) * cpx + (bid >> 3);
    const int by = swz / nbx, bx = swz - by * nbx;
    const size_t row0 = (size_t)by * 256, col0 = (size_t)bx * BN;
    const int nt = K >> 5;

    const int srow = tid >> 2;
    const int spc  = tid & 3;
    const int slx  = spc ^ ((srow >> 1) & 3);
    const __hip_bfloat16* Ab = A  + row0 * K;
    const __hip_bfloat16* Bb = Bt + col0 * K;

#define STGA(tile_) do {                                                                   \
    const int ss_ = (tile_) & 3;                                                           \
    const int kt_ = ((tile_) < nt) ? (tile_) : (nt - 1);                                   \
    _Pragma("unroll")                                                                      \
    for (int rh_ = 0; rh_ < 2; ++rh_)                                                      \
        __builtin_amdgcn_global_load_lds(                                                  \
            (const GAS void*)(Ab + (size_t)(rh_*128 + srow) * K + kt_*32 + slx*8),         \
            (LAS void*)&L[ss_*SLOT + rh_*4096 + w*512], 16, 0, 0);                         \
} while (0)

#define STGB(tile_) do {                                                                   \
    const int ss_ = (tile_) & 3;                                                           \
    const int kt_ = ((tile_) < nt) ? (tile_) : (nt - 1);                                   \
    _Pragma("unroll")                                                                      \
    for (int bh_ = 0; bh_ < BLD; ++bh_)                                                    \
        __builtin_amdgcn_global_load_lds(                                                  \
            (const GAS void*)(Bb + (size_t)(bh_*128 + srow) * K + kt_*32 + slx*8),         \
            (LAS void*)&L[ss_*SLOT + 8192 + bh_*4096 + w*512], 16, 0, 0);                  \
} while (0)

#define VMW2L() do {                                                                       \
    if constexpr (FN == 4) asm volatile("s_waitcnt vmcnt(8)" ::: "memory");                \
    else                   asm volatile("s_waitcnt vmcnt(6)" ::: "memory");                \
} while (0)

    f32x4 acc[2][4][FN] = {};
    bf16x8 afr0[4], afr1[4], bfr[FN];

    STGA(0); STGB(0); STGA(1); STGB(1); STGA(2); STGB(2);
    VMW2L();
    asm volatile("s_barrier" ::: "memory");

    for (int t = 0; t < nt; ++t) {
        const int s_ = t & 3;
        #pragma unroll
        for (int fn = 0; fn < FN; ++fn) {
            const int rB = wn*(FN*16) + fn*16 + lc;
            bfr[fn] = *(const bf16x8*)&L[s_*SLOT + 8192 + rB*32 + ((lg ^ ((rB >> 1) & 3)) * 8)];
        }
        #pragma unroll
        for (int fm = 0; fm < 4; ++fm) {
            const int rA = wm*128 + fm*16 + lc;
            afr0[fm] = *(const bf16x8*)&L[s_*SLOT + rA*32 + ((lg ^ ((rA >> 1) & 3)) * 8)];
        }
        __builtin_amdgcn_sched_barrier(0);
        #pragma unroll
        for (int fm = 0; fm < 4; ++fm) {
            const int rA = wm*128 + 64 + fm*16 + lc;
            afr1[fm] = *(const bf16x8*)&L[s_*SLOT + rA*32 + ((lg ^ ((rA >> 1) & 3)) * 8)];
        }
        STGA(t + 3);
        asm volatile("s_waitcnt lgkmcnt(4)" ::: "memory");
        __builtin_amdgcn_sched_barrier(0);
        __builtin_amdgcn_s_setprio(1);
        #pragma unroll
        for (int fm = 0; fm < 4; ++fm)
            #pragma unroll
            for (int fn = 0; fn < FN; ++fn)
                acc[0][fm][fn] = __builtin_amdgcn_mfma_f32_16x16x32_bf16(
                    afr0[fm], bfr[fn], acc[0][fm][fn], 0, 0, 0);
        __builtin_amdgcn_s_setprio(0);

        STGB(t + 3);
        asm volatile("s_waitcnt lgkmcnt(0)" ::: "memory");
        __builtin_amdgcn_sched_barrier(0);
        __builtin_amdgcn_s_setprio(1);
        #pragma unroll
        for (int fm = 0; fm < 4; ++fm)
            #pragma unroll
            for (int fn = 0; fn < FN; ++fn)
                acc[1][fm][fn] = __builtin_amdgcn_mfma_f32_16x16x32_bf16(
                    afr1[fm], bfr[fn], acc[1][fm][fn], 0, 0, 0);
        __builtin_amdgcn_s_setprio(0);
        VMW2L();
        asm volatile("s_barrier" ::: "memory");
    }
#undef STGA
#undef STGB
#undef VMW2L
    asm volatile("s_waitcnt vmcnt(0)" ::: "memory");

    if constexpr (OMODE == 2) {                         // KV fused (FN==2, BN=128)
        const int bb = (int)(row0 >> 11), s0 = (int)(row0 & 2047);
        if (bx < 8) {
            // ---- K head-slab: acc -> LDS [256][132] bf16, then per-row LN+RoPE -> kr
            const int g = bx;
            __hip_bfloat16* lt = (__hip_bfloat16*)L;
            __syncthreads();
            #pragma unroll
            for (int qm = 0; qm < 2; ++qm)
                #pragma unroll
                for (int fm = 0; fm < 4; ++fm)
                    #pragma unroll
                    for (int fn = 0; fn < FN; ++fn) {
                        const int cl = wn*32 + fn*16 + lc;
                        #pragma unroll
                        for (int rr = 0; rr < 4; ++rr) {
                            const int rl = wm*128 + qm*64 + fm*16 + lg*4 + rr;
                            lt[rl*132 + cl] = __float2bfloat16(acc[qm][fm][fn][rr]);
                        }
                    }
            __syncthreads();
            if (tid < 256) {
                const int s = s0 + tid;
                const __hip_bfloat16* rowp = &lt[tid*132];
                float sum = 0.f, ssq = 0.f;
                #pragma unroll
                for (int j = 0; j < 32; ++j) {
                    union { bf16x4 v; __hip_bfloat16 e[4]; } u;
                    u.v = *(const bf16x4*)(rowp + j*4);
                    #pragma unroll
                    for (int e = 0; e < 4; ++e) {
                        const float x = __bfloat162float(u.e[e]);
                        sum += x; ssq += x * x;
                    }
                }
                const float mu = sum * (1.f / D_);
                const float rs = rsqrtf(fmaxf(ssq * (1.f / D_) - mu*mu, 0.f) + 1e-5f);
                const int p = pids[bb*S_ + s];
                __hip_bfloat16* ko = (__hip_bfloat16*)Cv + (((size_t)bb*KVH_ + g)*S_ + s) * D_;
                #pragma unroll
                for (int j = 0; j < 16; ++j) {
                    union { bf16x8 v; __hip_bfloat16 e[8]; } u, o;
                    u.v = *(const bf16x8*)(rowp + j*8);
                    const int d0 = j*8;
                    float wl[8], cc[8], ss2[8], y[8];
                    *(float4*)&wl[0] = *(const float4*)(knw + d0);
                    *(float4*)&wl[4] = *(const float4*)(knw + d0 + 4);
                    *(float4*)&cc[0] = *(const float4*)(cosT + (size_t)p*D_ + d0);
                    *(float4*)&cc[4] = *(const float4*)(cosT + (size_t)p*D_ + d0 + 4);
                    *(float4*)&ss2[0] = *(const float4*)(sinT + (size_t)p*D_ + d0);
                    *(float4*)&ss2[4] = *(const float4*)(sinT + (size_t)p*D_ + d0 + 4);
                    #pragma unroll
                    for (int e = 0; e < 8; ++e)
                        y[e] = wl[e] * (__bfloat162float(u.e[e]) - mu) * rs;
                    #pragma unroll
                    for (int mp = 0; mp < 4; ++mp) {
                        o.e[2*mp]   = __float2bfloat16(y[2*mp]   * cc[2*mp]   - y[2*mp+1] * ss2[2*mp]);
                        o.e[2*mp+1] = __float2bfloat16(y[2*mp+1] * cc[2*mp+1] + y[2*mp]   * ss2[2*mp+1]);
                    }
                    *(bf16x8*)(ko + d0) = o.v;
                }
            }
        } else {                                        // V columns -> vt (B,KVH,D,S) via LDS
            __hip_bfloat16* lt = (__hip_bfloat16*)L;
            __syncthreads();
            #pragma unroll
            for (int qm = 0; qm < 2; ++qm)
                #pragma unroll
                for (int fm = 0; fm < 4; ++fm)
                    #pragma unroll
                    for (int fn = 0; fn < FN; ++fn) {
                        const int cl = wn*32 + fn*16 + lc;
                        #pragma unroll
                        for (int rr = 0; rr < 4; ++rr) {
                            const int rl = wm*128 + qm*64 + fm*16 + lg*4 + rr;
                            lt[cl*264 + rl] = __float2bfloat16(acc[qm][fm][fn][rr]);
                        }
                    }
            __syncthreads();
            const int g = (int)((col0 - 1024) >> 7);
            __hip_bfloat16* vto = (__hip_bfloat16*)C2 + (((size_t)bb*KVH_ + g) * D_) * (size_t)S_;
            const int d = tid >> 2, sc0 = (tid & 3) * 64;
            #pragma unroll
            for (int j = 0; j < 64; j += 8) {
                bf16x8 v = *(const bf16x8*)&lt[d*264 + sc0 + j];
                *(bf16x8*)&vto[(size_t)d*S_ + s0 + sc0 + j] = v;
            }
        }
    }
}

// chunk swizzle for attn K tile (16B chunks, 16/row)
static __device__ __forceinline__ int sigk_(int r) { return (r & 3) | ((r >> 1) & 4); }

// ------------------------------------------------- sliding-window GQA flash attention v4
// (unchanged — 8 waves / 128 q-rows, fused Q LN+RoPE, counted vmcnt staging)
__global__ __launch_bounds__(512, 4) void attn_fwd(const __hip_bfloat16* __restrict__ qfb,
                                                   const __hip_bfloat16* __restrict__ kr,
                                                   const __hip_bfloat16* __restrict__ vt,
                                                   const float* __restrict__ qnw,
                                                   const float* __restrict__ cosT,
                                                   const float* __restrict__ sinT,
                                                   const int* __restrict__ pids,
                                                   __hip_bfloat16* __restrict__ ao) {
    __shared__ __align__(16) __hip_bfloat16 Ksl[2][64*D_];    // 2 x 16KB
    __shared__ __align__(16) __hip_bfloat16 Vsl[2][D_*64];    // 2 x 16KB
    const int tid = threadIdx.x;
    const int lane = tid & 63, w = tid >> 6;     // 8 waves
    const int lq = lane & 15, lg = lane >> 4;
    const int blk = blockIdx.x;
    const int qt = blk & 15;
    const int bh = blk >> 4;
    const int h = bh & (H_-1), b = bh >> 5;
    const int g = h >> 2;
    const int q0 = qt*128 + w*16;
    const int q  = q0 + lq;

    const __hip_bfloat16* kbase = kr + ((size_t)b*KVH_ + g) * (size_t)S_ * D_;
    const __hip_bfloat16* vbase = vt + ((size_t)b*KVH_ + g) * (size_t)D_ * S_;

    const int srK = lane >> 4, scK = lane & 15;
    const int srV = lane >> 3, scV = lane & 7;

#define STAGE(nb, k0s) do {                                                              \
    _Pragma("unroll")                                                                    \
    for (int s_ = 0; s_ < 2; ++s_) {                                                     \
        const int rK_ = w*8 + s_*4 + srK;                                                \
        const __hip_bfloat16* srcK_ = kbase + (size_t)((k0s) + rK_)*D_                   \
                                      + ((scK ^ sigk_(rK_)) * 8);                        \
        __builtin_amdgcn_global_load_lds((const GAS void*)srcK_,                         \
            (LAS void*)&Ksl[nb][(w*8 + s_*4)*D_], 16, 0, 0);                             \
    }                                                                                    \
    _Pragma("unroll")                                                                    \
    for (int s_ = 0; s_ < 2; ++s_) {                                                     \
        const int dV_ = w*16 + s_*8 + srV;                                               \
        const __hip_bfloat16* srcV_ = vbase + (size_t)dV_*S_ + (k0s)                     \
                                      + ((scV ^ (dV_ & 7)) * 8);                         \
        __builtin_amdgcn_global_load_lds((const GAS void*)srcV_,                         \
            (LAS void*)&Vsl[nb][(w*16 + s_*8)*64], 16, 0, 0);                            \
    }                                                                                    \
} while (0)

    int kst = qt*128 - (WIN_ - 1); if (kst < 0) kst = 0; kst &= ~63;
    const int nt = qt*2 + 2 - (kst >> 6);

    union { bf16x8 v; __hip_bfloat16 e[8]; } qraw[4];
    const __hip_bfloat16* qb2 = qfb + ((size_t)(b*S_ + q)) * HID_ + h*D_;
    #pragma unroll
    for (int kk = 0; kk < 4; ++kk)
        qraw[kk].v = *(const bf16x8*)(qb2 + kk*32 + lg*8);
    const int p = pids[b*S_ + q];

    STAGE(0, kst);

    float sum = 0.f;
    #pragma unroll
    for (int kk = 0; kk < 4; ++kk)
        #pragma unroll
        for (int j = 0; j < 8; ++j) sum += __bfloat162float(qraw[kk].e[j]);
    sum += __shfl_xor(sum, 16); sum += __shfl_xor(sum, 32);
    const float mu = sum * (1.f / D_);
    float vsq = 0.f;
    #pragma unroll
    for (int kk = 0; kk < 4; ++kk)
        #pragma unroll
        for (int j = 0; j < 8; ++j) {
            const float dxx = __bfloat162float(qraw[kk].e[j]) - mu;
            vsq += dxx * dxx;
        }
    vsq += __shfl_xor(vsq, 16); vsq += __shfl_xor(vsq, 32);
    const float rsq = rsqrtf(vsq * (1.f / D_) + 1e-5f);

    bf16x8 qf[4];
    #pragma unroll
    for (int kk = 0; kk < 4; ++kk) {
        const int d0 = kk*32 + lg*8;
        float wl[8], cc[8], ss[8], y[8];
        *(float4*)&wl[0] = *(const float4*)(qnw + d0);
        *(float4*)&wl[4] = *(const float4*)(qnw + d0 + 4);
        *(float4*)&cc[0] = *(const float4*)(cosT + (size_t)p*D_ + d0);
        *(float4*)&cc[4] = *(const float4*)(cosT + (size_t)p*D_ + d0 + 4);
        *(float4*)&ss[0] = *(const float4*)(sinT + (size_t)p*D_ + d0);
        *(float4*)&ss[4] = *(const float4*)(sinT + (size_t)p*D_ + d0 + 4);
        #pragma unroll
        for (int j = 0; j < 8; ++j)
            y[j] = wl[j] * (__bfloat162float(qraw[kk].e[j]) - mu) * rsq;
        union { bf16x8 v; __hip_bfloat16 e[8]; } qo;
        #pragma unroll
        for (int mpair = 0; mpair < 4; ++mpair) {
            qo.e[2*mpair]   = __float2bfloat16(y[2*mpair]   * cc[2*mpair]   - y[2*mpair+1] * ss[2*mpair]);
            qo.e[2*mpair+1] = __float2bfloat16(y[2*mpair+1] * cc[2*mpair+1] + y[2*mpair]   * ss[2*mpair+1]);
        }
        qf[kk] = qo.v;
    }

    f32x4 o[8] = {};
    float m = -1e30f, l = 0.f;
    const int kldrow = 8*(lq >> 2) + (lq & 3);

    for (int t = 0; t < nt; ++t) {
        const int k0 = kst + t*64;
        const int buf = t & 1;
        if (t + 1 < nt) {
            STAGE((t + 1) & 1, k0 + 64);
            asm volatile("s_waitcnt vmcnt(4)" ::: "memory");
        } else {
            asm volatile("s_waitcnt vmcnt(0)" ::: "memory");
        }
        __builtin_amdgcn_s_barrier();

        f32x4 sc[2][2] = {};
        __builtin_amdgcn_s_setprio(1);
        #pragma unroll
        for (int kb = 0; kb < 2; ++kb)
            #pragma unroll
            for (int f = 0; f < 2; ++f) {
                const int rA = kb*32 + 4*f + kldrow;
                const __hip_bfloat16* kp = &Ksl[buf][rA*D_];
                #pragma unroll
                for (int kk = 0; kk < 4; ++kk) {
                    bf16x8 ka = *(const bf16x8*)(kp + (((kk*4 + lg) ^ sigk_(rA)) * 8));
                    sc[kb][f] = __builtin_amdgcn_mfma_f32_16x16x32_bf16(ka, qf[kk], sc[kb][f], 0, 0, 0);
                }
            }
        __builtin_amdgcn_s_setprio(0);

        const int dqk = q - (k0 + 8*lg);
        float pv[16];
        float mx = -INFINITY;
        #pragma unroll
        for (int kb = 0; kb < 2; ++kb)
            #pragma unroll
            for (int f = 0; f < 2; ++f)
                #pragma unroll
                for (int r = 0; r < 4; ++r) {
                    const int c = kb*32 + 4*f + r;
                    const int d = dqk - c;
                    float v = (d >= 0 && d < WIN_) ? sc[kb][f][r] * SL2E_ : -INFINITY;
                    pv[kb*8 + f*4 + r] = v;
                    mx = fmaxf(mx, v);
                }
        mx = fmaxf(mx, __shfl_xor(mx, 16));
        mx = fmaxf(mx, __shfl_xor(mx, 32));
        const float mn = fmaxf(m, mx);
        const float alpha = exp2f(m - mn);
        float ls = 0.f;
        union { bf16x8 v; __hip_bfloat16 e[8]; } pu[2];
        #pragma unroll
        for (int kb = 0; kb < 2; ++kb)
            #pragma unroll
            for (int j = 0; j < 8; ++j) {
                const float pw = exp2f(pv[kb*8 + j] - mn);
                ls += pw;
                pu[kb].e[j] = __float2bfloat16(pw);
            }
        ls += __shfl_xor(ls, 16);
        ls += __shfl_xor(ls, 32);
        l = l * alpha + ls;
        m = mn;
        #pragma unroll
        for (int n = 0; n < 8; ++n) {
            o[n][0] *= alpha; o[n][1] *= alpha; o[n][2] *= alpha; o[n][3] *= alpha;
        }

        __builtin_amdgcn_s_setprio(1);
        #pragma unroll
        for (int kb = 0; kb < 2; ++kb)
            #pragma unroll
            for (int n = 0; n < 8; ++n) {
                const int dR = n*16 + lq;
                bf16x8 vf8 = *(const bf16x8*)(&Vsl[buf][dR*64] + (((kb*4 + lg) ^ (dR & 7)) * 8));
                o[n] = __builtin_amdgcn_mfma_f32_16x16x32_bf16(vf8, pu[kb].v, o[n], 0, 0, 0);
            }
        __builtin_amdgcn_s_setprio(0);

        if (t + 1 < nt) __builtin_amdgcn_s_barrier();
    }
#undef STAGE

    const float rinv = 1.f / l;
    #pragma unroll
    for (int n = 0; n < 8; ++n) {
        union { bf16x4 v; __hip_bfloat16 e[4]; } ov;
        #pragma unroll
        for (int r = 0; r < 4; ++r) ov.e[r] = __float2bfloat16(o[n][r] * rinv);
        *(bf16x4*)(ao + ((size_t)b*S_ + q)*(H_*D_) + h*D_ + n*16 + lg*4) = ov.v;
    }
}

// ----------------------------------------------------------------- host
extern "C" void kernel_launch(void* const* d_in, const int* in_sizes, int n_in,
                              void* d_out, int out_size, void* d_ws, size_t ws_size,
                              hipStream_t stream) {
    const float* hidden = (const float*)d_in[0];
    const int*   pids   = (const int*)  d_in[1];
    const float* cosT   = (const float*)d_in[2];
    const float* sinT   = (const float*)d_in[3];
    const float* wq     = (const float*)d_in[4];
    const float* wk     = (const float*)d_in[5];
    const float* wv     = (const float*)d_in[6];
    const float* wo     = (const float*)d_in[7];
    const float* qnw    = (const float*)d_in[8];
    const float* knw    = (const float*)d_in[9];
    float* out = (float*)d_out;

    char* base = (char*)d_ws;
    size_t off = 0;
    auto take = [&](size_t bytes) -> void* {
        void* q = base + off;
        off = (off + bytes + 255) & ~(size_t)255;
        return q;
    };
    __hip_bfloat16* qfb  = (__hip_bfloat16*)take((size_t)NROW_*HID_*2);   // Q proj bf16
    __hip_bfloat16* ao   = (__hip_bfloat16*)take((size_t)NROW_*HID_*2);   // attn out bf16
    __hip_bfloat16* hb   = (__hip_bfloat16*)take((size_t)NROW_*HID_*2);
    __hip_bfloat16* wqT  = (__hip_bfloat16*)take((size_t)HID_*HID_*2);
    __hip_bfloat16* wkvT = (__hip_bfloat16*)take((size_t)NKV_*HID_*2);
    __hip_bfloat16* woT  = (__hip_bfloat16*)take((size_t)HID_*HID_*2);
    __hip_bfloat16* kr   = (__hip_bfloat16*)take((size_t)B_*KVH_*S_*D_*2);
    __hip_bfloat16* vt   = (__hip_bfloat16*)take((size_t)B_*KVH_*S_*D_*2);

    if (off > ws_size) {
        fprintf(stderr, "WORKSPACE TOO SMALL: need %zu have %zu\n", off, ws_size);
        return;
    }

    // 1. merged prep: hidden convert + 4 weight transposes (1 launch)
    prep_all<<<16384 + 40960, 256, 0, stream>>>(hidden, wq, wk, wv, wo, hb, wqT, wkvT, woT);

    // 2. projections.  Q/WO: 128x256 tiles, 512 blocks = 2 resident blocks/CU (cross-block
    //    pipe overlap).  KV: proven ring-4 kernel with fused K-LN/RoPE + V-transpose.
    gemm128<1><<<(NROW_/128)*(HID_/256), 512, 0, stream>>>(hb, wqT, qfb, NROW_, HID_, HID_, HID_/256);
    gemm_t<2,2><<<(NROW_/256)*(NKV_/128), 512, 0, stream>>>(hb, wkvT, kr, vt,
        knw, cosT, sinT, pids, NROW_, NKV_, HID_, NKV_/128);

    // 3. attention (8 waves, 128 q-rows/block, fused Q LN+RoPE)
    attn_fwd<<<B_*H_*(S_/128), 512, 0, stream>>>(qfb, kr, vt, qnw, cosT, sinT, pids, ao);

    // 4. output projection -> d_out (f32)
    gemm128<0><<<(NROW_/128)*(HID_/256), 512, 0, stream>>>(ao, woT, out, NROW_, HID_, H_*D_, HID_/256);
}

// Round 16
// 490.924 us; speedup vs baseline: 1.0285x; 1.0285x over previous
//
#include <hip/hip_runtime.h>
#include <hip/hip_bf16.h>
#include <cstdio>
#include <cstdint>

#define B_    2
#define S_    2048
#define H_    32
#define KVH_  8
#define D_    128
#define HID_  4096
#define WIN_  512
#define NROW_ (B_*S_)          // 4096 rows for projection GEMMs
#define NKV_  2048             // fused k|v output width
#define SCALE_ 0.08838834764831845f          // 128^-0.5
#define SL2E_  0.12751744932973953f          // SCALE_ * log2(e)

typedef __attribute__((ext_vector_type(8))) __bf16 bf16x8;
typedef __attribute__((ext_vector_type(4))) __bf16 bf16x4;
typedef __attribute__((ext_vector_type(4))) float  f32x4;

#define GAS __attribute__((address_space(1)))
#define LAS __attribute__((address_space(3)))

// ------------------------------------------------- merged prep: cvt hidden + 4 weight transposes
__global__ __launch_bounds__(256) void prep_all(const float* __restrict__ hidden,
                                                const float* __restrict__ wq,
                                                const float* __restrict__ wk,
                                                const float* __restrict__ wv,
                                                const float* __restrict__ wo,
                                                __hip_bfloat16* __restrict__ hb,
                                                __hip_bfloat16* __restrict__ wqT,
                                                __hip_bfloat16* __restrict__ wkvT,
                                                __hip_bfloat16* __restrict__ woT) {
    __shared__ float t[32][33];
    const int bid = blockIdx.x;
    if (bid < 16384) {
        const int i = (bid * 256 + threadIdx.x) * 4;
        float4 v = *(const float4*)(hidden + i);
        __hip_bfloat162 a, b;
        a.x = __float2bfloat16(v.x); a.y = __float2bfloat16(v.y);
        b.x = __float2bfloat16(v.z); b.y = __float2bfloat16(v.w);
        *(__hip_bfloat162*)(hb + i)     = a;
        *(__hip_bfloat162*)(hb + i + 2) = b;
        return;
    }
    const int tx = threadIdx.x & 31, ty = threadIdx.x >> 5;
    const int id = bid - 16384;
    const float* src; __hip_bfloat16* dst; int C, idx;   // R always 4096
    if (id < 16384)      { src = wq; dst = wqT;  C = 4096; idx = id; }
    else if (id < 20480) { src = wk; dst = wkvT; C = 1024; idx = id - 16384; }
    else if (id < 24576) { src = wv; dst = wkvT + (size_t)1024*HID_; C = 1024; idx = id - 20480; }
    else                 { src = wo; dst = woT;  C = 4096; idx = id - 24576; }
    const int ctiles = C >> 5;
    const int c0 = (idx % ctiles) * 32, r0 = (idx / ctiles) * 32;
    #pragma unroll
    for (int i = 0; i < 4; ++i)
        t[ty + 8*i][tx] = src[(size_t)(r0 + ty + 8*i) * C + c0 + tx];
    __syncthreads();
    #pragma unroll
    for (int i = 0; i < 4; ++i)
        dst[(size_t)(c0 + ty + 8*i) * HID_ + r0 + tx] = __float2bfloat16(t[tx][ty + 8*i]);
}

// ------------------------------------------------- GEMM 256xBN, BK=32, ring-4, 1-barrier/tile
// R10-proven schedule (best measured: MfmaUtil ~49%, 125us @ 4096x4096x4096).
// OMODE 0: f32 out.  1: bf16 out.  2: KV fused — bx<8: K head-slab LayerNorm+RoPE
// in-epilogue -> kr; bx>=8: V cols transposed via LDS -> vt (B,KVH,D,S).
template <int FN, int OMODE>
__global__ __launch_bounds__(512, 2) void gemm_t(const __hip_bfloat16* __restrict__ A,
                                                 const __hip_bfloat16* __restrict__ Bt,
                                                 void* __restrict__ Cv, void* __restrict__ C2,
                                                 const float* __restrict__ knw,
                                                 const float* __restrict__ cosT,
                                                 const float* __restrict__ sinT,
                                                 const int* __restrict__ pids,
                                                 int M, int N, int K, int nbx) {
    constexpr int BN   = FN * 64;
    constexpr int BLD  = BN / 128;                      // B stage loads/thread/tile (2 or 1)
    constexpr int SLOT = (256 + BN) * 32;               // elems per ring slot (A then B)
    __shared__ __align__(16) __hip_bfloat16 L[4 * SLOT];
    const int tid  = threadIdx.x;
    const int lane = tid & 63, w = tid >> 6;
    const int wm = w >> 2, wn = w & 3;                  // 2 x 4 wave grid
    const int lc = lane & 15, lg = lane >> 4;
    const int nwg = gridDim.x, cpx = nwg >> 3;
    const int bid = blockIdx.x;
    const int swz = (bid & 7) * cpx + (bid >> 3);
    const int by = swz / nbx, bx = swz - by * nbx;
    const size_t row0 = (size_t)by * 256, col0 = (size_t)bx * BN;
    const int nt = K >> 5;                              // BK = 32

    const int srow = tid >> 2;
    const int spc  = tid & 3;
    const int slx  = spc ^ ((srow >> 1) & 3);
    const __hip_bfloat16* Ab = A  + row0 * K;
    const __hip_bfloat16* Bb = Bt + col0 * K;

#define STGA(tile_) do {                                                                   \
    const int ss_ = (tile_) & 3;                                                           \
    const int kt_ = ((tile_) < nt) ? (tile_) : (nt - 1);                                   \
    _Pragma("unroll")                                                                      \
    for (int rh_ = 0; rh_ < 2; ++rh_)                                                      \
        __builtin_amdgcn_global_load_lds(                                                  \
            (const GAS void*)(Ab + (size_t)(rh_*128 + srow) * K + kt_*32 + slx*8),         \
            (LAS void*)&L[ss_*SLOT + rh_*4096 + w*512], 16, 0, 0);                         \
} while (0)

#define STGB(tile_) do {                                                                   \
    const int ss_ = (tile_) & 3;                                                           \
    const int kt_ = ((tile_) < nt) ? (tile_) : (nt - 1);                                   \
    _Pragma("unroll")                                                                      \
    for (int bh_ = 0; bh_ < BLD; ++bh_)                                                    \
        __builtin_amdgcn_global_load_lds(                                                  \
            (const GAS void*)(Bb + (size_t)(bh_*128 + srow) * K + kt_*32 + slx*8),         \
            (LAS void*)&L[ss_*SLOT + 8192 + bh_*4096 + w*512], 16, 0, 0);                  \
} while (0)

#define VMW2L() do {                                                                       \
    if constexpr (FN == 4) asm volatile("s_waitcnt vmcnt(8)" ::: "memory");                \
    else                   asm volatile("s_waitcnt vmcnt(6)" ::: "memory");                \
} while (0)

    f32x4 acc[2][4][FN] = {};
    bf16x8 afr0[4], afr1[4], bfr[FN];

    STGA(0); STGB(0); STGA(1); STGB(1); STGA(2); STGB(2);
    VMW2L();
    asm volatile("s_barrier" ::: "memory");

    for (int t = 0; t < nt; ++t) {
        const int s_ = t & 3;
        #pragma unroll
        for (int fn = 0; fn < FN; ++fn) {
            const int rB = wn*(FN*16) + fn*16 + lc;
            bfr[fn] = *(const bf16x8*)&L[s_*SLOT + 8192 + rB*32 + ((lg ^ ((rB >> 1) & 3)) * 8)];
        }
        #pragma unroll
        for (int fm = 0; fm < 4; ++fm) {
            const int rA = wm*128 + fm*16 + lc;
            afr0[fm] = *(const bf16x8*)&L[s_*SLOT + rA*32 + ((lg ^ ((rA >> 1) & 3)) * 8)];
        }
        __builtin_amdgcn_sched_barrier(0);
        #pragma unroll
        for (int fm = 0; fm < 4; ++fm) {
            const int rA = wm*128 + 64 + fm*16 + lc;
            afr1[fm] = *(const bf16x8*)&L[s_*SLOT + rA*32 + ((lg ^ ((rA >> 1) & 3)) * 8)];
        }
        STGA(t + 3);
        asm volatile("s_waitcnt lgkmcnt(4)" ::: "memory");
        __builtin_amdgcn_sched_barrier(0);
        __builtin_amdgcn_s_setprio(1);
        #pragma unroll
        for (int fm = 0; fm < 4; ++fm)
            #pragma unroll
            for (int fn = 0; fn < FN; ++fn)
                acc[0][fm][fn] = __builtin_amdgcn_mfma_f32_16x16x32_bf16(
                    afr0[fm], bfr[fn], acc[0][fm][fn], 0, 0, 0);
        __builtin_amdgcn_s_setprio(0);

        STGB(t + 3);
        asm volatile("s_waitcnt lgkmcnt(0)" ::: "memory");
        __builtin_amdgcn_sched_barrier(0);
        __builtin_amdgcn_s_setprio(1);
        #pragma unroll
        for (int fm = 0; fm < 4; ++fm)
            #pragma unroll
            for (int fn = 0; fn < FN; ++fn)
                acc[1][fm][fn] = __builtin_amdgcn_mfma_f32_16x16x32_bf16(
                    afr1[fm], bfr[fn], acc[1][fm][fn], 0, 0, 0);
        __builtin_amdgcn_s_setprio(0);
        VMW2L();
        asm volatile("s_barrier" ::: "memory");
    }
#undef STGA
#undef STGB
#undef VMW2L
    asm volatile("s_waitcnt vmcnt(0)" ::: "memory");

    if constexpr (OMODE == 0) {
        float* C = (float*)Cv;
        #pragma unroll
        for (int qm = 0; qm < 2; ++qm)
            #pragma unroll
            for (int fm = 0; fm < 4; ++fm)
                #pragma unroll
                for (int fn = 0; fn < FN; ++fn) {
                    const size_t col = col0 + wn*(FN*16) + fn*16 + lc;
                    #pragma unroll
                    for (int rr = 0; rr < 4; ++rr) {
                        const size_t row = row0 + wm*128 + qm*64 + fm*16 + lg*4 + rr;
                        C[row * N + col] = acc[qm][fm][fn][rr];
                    }
                }
    } else if constexpr (OMODE == 1) {
        __hip_bfloat16* C = (__hip_bfloat16*)Cv;
        #pragma unroll
        for (int qm = 0; qm < 2; ++qm)
            #pragma unroll
            for (int fm = 0; fm < 4; ++fm)
                #pragma unroll
                for (int fn = 0; fn < FN; ++fn) {
                    const size_t col = col0 + wn*(FN*16) + fn*16 + lc;
                    #pragma unroll
                    for (int rr = 0; rr < 4; ++rr) {
                        const size_t row = row0 + wm*128 + qm*64 + fm*16 + lg*4 + rr;
                        C[row * N + col] = __float2bfloat16(acc[qm][fm][fn][rr]);
                    }
                }
    } else {                                            // OMODE 2: KV fused (FN==2, BN=128)
        const int bb = (int)(row0 >> 11), s0 = (int)(row0 & 2047);
        if (bx < 8) {
            // ---- K head-slab: acc -> LDS [256][132] bf16, then per-row LN+RoPE -> kr
            const int g = bx;
            __hip_bfloat16* lt = (__hip_bfloat16*)L;
            __syncthreads();
            #pragma unroll
            for (int qm = 0; qm < 2; ++qm)
                #pragma unroll
                for (int fm = 0; fm < 4; ++fm)
                    #pragma unroll
                    for (int fn = 0; fn < FN; ++fn) {
                        const int cl = wn*32 + fn*16 + lc;
                        #pragma unroll
                        for (int rr = 0; rr < 4; ++rr) {
                            const int rl = wm*128 + qm*64 + fm*16 + lg*4 + rr;
                            lt[rl*132 + cl] = __float2bfloat16(acc[qm][fm][fn][rr]);
                        }
                    }
            __syncthreads();
            if (tid < 256) {
                const int s = s0 + tid;
                const __hip_bfloat16* rowp = &lt[tid*132];
                float sum = 0.f, ssq = 0.f;
                #pragma unroll
                for (int j = 0; j < 32; ++j) {
                    union { bf16x4 v; __hip_bfloat16 e[4]; } u;
                    u.v = *(const bf16x4*)(rowp + j*4);
                    #pragma unroll
                    for (int e = 0; e < 4; ++e) {
                        const float x = __bfloat162float(u.e[e]);
                        sum += x; ssq += x * x;
                    }
                }
                const float mu = sum * (1.f / D_);
                const float rs = rsqrtf(fmaxf(ssq * (1.f / D_) - mu*mu, 0.f) + 1e-5f);
                const int p = pids[bb*S_ + s];
                __hip_bfloat16* ko = (__hip_bfloat16*)Cv + (((size_t)bb*KVH_ + g)*S_ + s) * D_;
                #pragma unroll
                for (int j = 0; j < 16; ++j) {
                    union { bf16x8 v; __hip_bfloat16 e[8]; } u, o;
                    u.v = *(const bf16x8*)(rowp + j*8);
                    const int d0 = j*8;
                    float wl[8], cc[8], ss2[8], y[8];
                    *(float4*)&wl[0] = *(const float4*)(knw + d0);
                    *(float4*)&wl[4] = *(const float4*)(knw + d0 + 4);
                    *(float4*)&cc[0] = *(const float4*)(cosT + (size_t)p*D_ + d0);
                    *(float4*)&cc[4] = *(const float4*)(cosT + (size_t)p*D_ + d0 + 4);
                    *(float4*)&ss2[0] = *(const float4*)(sinT + (size_t)p*D_ + d0);
                    *(float4*)&ss2[4] = *(const float4*)(sinT + (size_t)p*D_ + d0 + 4);
                    #pragma unroll
                    for (int e = 0; e < 8; ++e)
                        y[e] = wl[e] * (__bfloat162float(u.e[e]) - mu) * rs;
                    #pragma unroll
                    for (int mp = 0; mp < 4; ++mp) {
                        o.e[2*mp]   = __float2bfloat16(y[2*mp]   * cc[2*mp]   - y[2*mp+1] * ss2[2*mp]);
                        o.e[2*mp+1] = __float2bfloat16(y[2*mp+1] * cc[2*mp+1] + y[2*mp]   * ss2[2*mp+1]);
                    }
                    *(bf16x8*)(ko + d0) = o.v;
                }
            }
        } else {                                        // V columns -> vt (B,KVH,D,S) via LDS
            __hip_bfloat16* lt = (__hip_bfloat16*)L;
            __syncthreads();
            #pragma unroll
            for (int qm = 0; qm < 2; ++qm)
                #pragma unroll
                for (int fm = 0; fm < 4; ++fm)
                    #pragma unroll
                    for (int fn = 0; fn < FN; ++fn) {
                        const int cl = wn*32 + fn*16 + lc;
                        #pragma unroll
                        for (int rr = 0; rr < 4; ++rr) {
                            const int rl = wm*128 + qm*64 + fm*16 + lg*4 + rr;
                            lt[cl*264 + rl] = __float2bfloat16(acc[qm][fm][fn][rr]);
                        }
                    }
            __syncthreads();
            const int g = (int)((col0 - 1024) >> 7);
            __hip_bfloat16* vto = (__hip_bfloat16*)C2 + (((size_t)bb*KVH_ + g) * D_) * (size_t)S_;
            const int d = tid >> 2, sc0 = (tid & 3) * 64;
            #pragma unroll
            for (int j = 0; j < 64; j += 8) {
                bf16x8 v = *(const bf16x8*)&lt[d*264 + sc0 + j];
                *(bf16x8*)&vto[(size_t)d*S_ + s0 + sc0 + j] = v;
            }
        }
    }
}

// chunk swizzle for attn K tile (16B chunks, 16/row)
static __device__ __forceinline__ int sigk_(int r) { return (r & 3) | ((r >> 1) & 4); }

// ------------------------------------------------- sliding-window GQA flash attention v4
// 8 waves / 128 q-rows per block, fused Q LN+RoPE, counted vmcnt staging.
// launch_bounds (512,2): LDS (64 KiB) already caps residency at 2 blocks/CU; this removes
// the 128-VGPR clamp so the allocator avoids spills (R15 showed VGPR squeezed to 64).
__global__ __launch_bounds__(512, 2) void attn_fwd(const __hip_bfloat16* __restrict__ qfb,
                                                   const __hip_bfloat16* __restrict__ kr,
                                                   const __hip_bfloat16* __restrict__ vt,
                                                   const float* __restrict__ qnw,
                                                   const float* __restrict__ cosT,
                                                   const float* __restrict__ sinT,
                                                   const int* __restrict__ pids,
                                                   __hip_bfloat16* __restrict__ ao) {
    __shared__ __align__(16) __hip_bfloat16 Ksl[2][64*D_];    // 2 x 16KB
    __shared__ __align__(16) __hip_bfloat16 Vsl[2][D_*64];    // 2 x 16KB
    const int tid = threadIdx.x;
    const int lane = tid & 63, w = tid >> 6;     // 8 waves
    const int lq = lane & 15, lg = lane >> 4;
    const int blk = blockIdx.x;
    const int qt = blk & 15;
    const int bh = blk >> 4;
    const int h = bh & (H_-1), b = bh >> 5;
    const int g = h >> 2;
    const int q0 = qt*128 + w*16;
    const int q  = q0 + lq;

    const __hip_bfloat16* kbase = kr + ((size_t)b*KVH_ + g) * (size_t)S_ * D_;
    const __hip_bfloat16* vbase = vt + ((size_t)b*KVH_ + g) * (size_t)D_ * S_;

    const int srK = lane >> 4, scK = lane & 15;
    const int srV = lane >> 3, scV = lane & 7;

#define STAGE(nb, k0s) do {                                                              \
    _Pragma("unroll")                                                                    \
    for (int s_ = 0; s_ < 2; ++s_) {                                                     \
        const int rK_ = w*8 + s_*4 + srK;                                                \
        const __hip_bfloat16* srcK_ = kbase + (size_t)((k0s) + rK_)*D_                   \
                                      + ((scK ^ sigk_(rK_)) * 8);                        \
        __builtin_amdgcn_global_load_lds((const GAS void*)srcK_,                         \
            (LAS void*)&Ksl[nb][(w*8 + s_*4)*D_], 16, 0, 0);                             \
    }                                                                                    \
    _Pragma("unroll")                                                                    \
    for (int s_ = 0; s_ < 2; ++s_) {                                                     \
        const int dV_ = w*16 + s_*8 + srV;                                               \
        const __hip_bfloat16* srcV_ = vbase + (size_t)dV_*S_ + (k0s)                     \
                                      + ((scV ^ (dV_ & 7)) * 8);                         \
        __builtin_amdgcn_global_load_lds((const GAS void*)srcV_,                         \
            (LAS void*)&Vsl[nb][(w*16 + s_*8)*64], 16, 0, 0);                            \
    }                                                                                    \
} while (0)

    int kst = qt*128 - (WIN_ - 1); if (kst < 0) kst = 0; kst &= ~63;
    const int nt = qt*2 + 2 - (kst >> 6);

    union { bf16x8 v; __hip_bfloat16 e[8]; } qraw[4];
    const __hip_bfloat16* qb2 = qfb + ((size_t)(b*S_ + q)) * HID_ + h*D_;
    #pragma unroll
    for (int kk = 0; kk < 4; ++kk)
        qraw[kk].v = *(const bf16x8*)(qb2 + kk*32 + lg*8);
    const int p = pids[b*S_ + q];

    STAGE(0, kst);

    float sum = 0.f;
    #pragma unroll
    for (int kk = 0; kk < 4; ++kk)
        #pragma unroll
        for (int j = 0; j < 8; ++j) sum += __bfloat162float(qraw[kk].e[j]);
    sum += __shfl_xor(sum, 16); sum += __shfl_xor(sum, 32);
    const float mu = sum * (1.f / D_);
    float vsq = 0.f;
    #pragma unroll
    for (int kk = 0; kk < 4; ++kk)
        #pragma unroll
        for (int j = 0; j < 8; ++j) {
            const float dxx = __bfloat162float(qraw[kk].e[j]) - mu;
            vsq += dxx * dxx;
        }
    vsq += __shfl_xor(vsq, 16); vsq += __shfl_xor(vsq, 32);
    const float rsq = rsqrtf(vsq * (1.f / D_) + 1e-5f);

    bf16x8 qf[4];
    #pragma unroll
    for (int kk = 0; kk < 4; ++kk) {
        const int d0 = kk*32 + lg*8;
        float wl[8], cc[8], ss[8], y[8];
        *(float4*)&wl[0] = *(const float4*)(qnw + d0);
        *(float4*)&wl[4] = *(const float4*)(qnw + d0 + 4);
        *(float4*)&cc[0] = *(const float4*)(cosT + (size_t)p*D_ + d0);
        *(float4*)&cc[4] = *(const float4*)(cosT + (size_t)p*D_ + d0 + 4);
        *(float4*)&ss[0] = *(const float4*)(sinT + (size_t)p*D_ + d0);
        *(float4*)&ss[4] = *(const float4*)(sinT + (size_t)p*D_ + d0 + 4);
        #pragma unroll
        for (int j = 0; j < 8; ++j)
            y[j] = wl[j] * (__bfloat162float(qraw[kk].e[j]) - mu) * rsq;
        union { bf16x8 v; __hip_bfloat16 e[8]; } qo;
        #pragma unroll
        for (int mpair = 0; mpair < 4; ++mpair) {
            qo.e[2*mpair]   = __float2bfloat16(y[2*mpair]   * cc[2*mpair]   - y[2*mpair+1] * ss[2*mpair]);
            qo.e[2*mpair+1] = __float2bfloat16(y[2*mpair+1] * cc[2*mpair+1] + y[2*mpair]   * ss[2*mpair+1]);
        }
        qf[kk] = qo.v;
    }

    f32x4 o[8] = {};
    float m = -1e30f, l = 0.f;
    const int kldrow = 8*(lq >> 2) + (lq & 3);

    for (int t = 0; t < nt; ++t) {
        const int k0 = kst + t*64;
        const int buf = t & 1;
        if (t + 1 < nt) {
            STAGE((t + 1) & 1, k0 + 64);
            asm volatile("s_waitcnt vmcnt(4)" ::: "memory");
        } else {
            asm volatile("s_waitcnt vmcnt(0)" ::: "memory");
        }
        __builtin_amdgcn_s_barrier();

        f32x4 sc[2][2] = {};
        __builtin_amdgcn_s_setprio(1);
        #pragma unroll
        for (int kb = 0; kb < 2; ++kb)
            #pragma unroll
            for (int f = 0; f < 2; ++f) {
                const int rA = kb*32 + 4*f + kldrow;
                const __hip_bfloat16* kp = &Ksl[buf][rA*D_];
                #pragma unroll
                for (int kk = 0; kk < 4; ++kk) {
                    bf16x8 ka = *(const bf16x8*)(kp + (((kk*4 + lg) ^ sigk_(rA)) * 8));
                    sc[kb][f] = __builtin_amdgcn_mfma_f32_16x16x32_bf16(ka, qf[kk], sc[kb][f], 0, 0, 0);
                }
            }
        __builtin_amdgcn_s_setprio(0);

        const int dqk = q - (k0 + 8*lg);
        float pv[16];
        float mx = -INFINITY;
        #pragma unroll
        for (int kb = 0; kb < 2; ++kb)
            #pragma unroll
            for (int f = 0; f < 2; ++f)
                #pragma unroll
                for (int r = 0; r < 4; ++r) {
                    const int c = kb*32 + 4*f + r;
                    const int d = dqk - c;
                    float v = (d >= 0 && d < WIN_) ? sc[kb][f][r] * SL2E_ : -INFINITY;
                    pv[kb*8 + f*4 + r] = v;
                    mx = fmaxf(mx, v);
                }
        mx = fmaxf(mx, __shfl_xor(mx, 16));
        mx = fmaxf(mx, __shfl_xor(mx, 32));
        const float mn = fmaxf(m, mx);
        const float alpha = exp2f(m - mn);
        float ls = 0.f;
        union { bf16x8 v; __hip_bfloat16 e[8]; } pu[2];
        #pragma unroll
        for (int kb = 0; kb < 2; ++kb)
            #pragma unroll
            for (int j = 0; j < 8; ++j) {
                const float pw = exp2f(pv[kb*8 + j] - mn);
                ls += pw;
                pu[kb].e[j] = __float2bfloat16(pw);
            }
        ls += __shfl_xor(ls, 16);
        ls += __shfl_xor(ls, 32);
        l = l * alpha + ls;
        m = mn;
        #pragma unroll
        for (int n = 0; n < 8; ++n) {
            o[n][0] *= alpha; o[n][1] *= alpha; o[n][2] *= alpha; o[n][3] *= alpha;
        }

        __builtin_amdgcn_s_setprio(1);
        #pragma unroll
        for (int kb = 0; kb < 2; ++kb)
            #pragma unroll
            for (int n = 0; n < 8; ++n) {
                const int dR = n*16 + lq;
                bf16x8 vf8 = *(const bf16x8*)(&Vsl[buf][dR*64] + (((kb*4 + lg) ^ (dR & 7)) * 8));
                o[n] = __builtin_amdgcn_mfma_f32_16x16x32_bf16(vf8, pu[kb].v, o[n], 0, 0, 0);
            }
        __builtin_amdgcn_s_setprio(0);

        if (t + 1 < nt) __builtin_amdgcn_s_barrier();
    }
#undef STAGE

    const float rinv = 1.f / l;
    #pragma unroll
    for (int n = 0; n < 8; ++n) {
        union { bf16x4 v; __hip_bfloat16 e[4]; } ov;
        #pragma unroll
        for (int r = 0; r < 4; ++r) ov.e[r] = __float2bfloat16(o[n][r] * rinv);
        *(bf16x4*)(ao + ((size_t)b*S_ + q)*(H_*D_) + h*D_ + n*16 + lg*4) = ov.v;
    }
}

// ----------------------------------------------------------------- host
extern "C" void kernel_launch(void* const* d_in, const int* in_sizes, int n_in,
                              void* d_out, int out_size, void* d_ws, size_t ws_size,
                              hipStream_t stream) {
    const float* hidden = (const float*)d_in[0];
    const int*   pids   = (const int*)  d_in[1];
    const float* cosT   = (const float*)d_in[2];
    const float* sinT   = (const float*)d_in[3];
    const float* wq     = (const float*)d_in[4];
    const float* wk     = (const float*)d_in[5];
    const float* wv     = (const float*)d_in[6];
    const float* wo     = (const float*)d_in[7];
    const float* qnw    = (const float*)d_in[8];
    const float* knw    = (const float*)d_in[9];
    float* out = (float*)d_out;

    char* base = (char*)d_ws;
    size_t off = 0;
    auto take = [&](size_t bytes) -> void* {
        void* q = base + off;
        off = (off + bytes + 255) & ~(size_t)255;
        return q;
    };
    __hip_bfloat16* qfb  = (__hip_bfloat16*)take((size_t)NROW_*HID_*2);   // Q proj bf16
    __hip_bfloat16* ao   = (__hip_bfloat16*)take((size_t)NROW_*HID_*2);   // attn out bf16
    __hip_bfloat16* hb   = (__hip_bfloat16*)take((size_t)NROW_*HID_*2);
    __hip_bfloat16* wqT  = (__hip_bfloat16*)take((size_t)HID_*HID_*2);
    __hip_bfloat16* wkvT = (__hip_bfloat16*)take((size_t)NKV_*HID_*2);
    __hip_bfloat16* woT  = (__hip_bfloat16*)take((size_t)HID_*HID_*2);
    __hip_bfloat16* kr   = (__hip_bfloat16*)take((size_t)B_*KVH_*S_*D_*2);
    __hip_bfloat16* vt   = (__hip_bfloat16*)take((size_t)B_*KVH_*S_*D_*2);

    if (off > ws_size) {
        fprintf(stderr, "WORKSPACE TOO SMALL: need %zu have %zu\n", off, ws_size);
        return;
    }

    // 1. merged prep: hidden convert + 4 weight transposes (1 launch)
    prep_all<<<16384 + 40960, 256, 0, stream>>>(hidden, wq, wk, wv, wo, hb, wqT, wkvT, woT);

    // 2. projections — every grid exactly 256 blocks (1 round on 256 CUs).
    //    KV GEMM fuses K LayerNorm+RoPE (writes kr) and V transpose (writes vt) in-epilogue.
    gemm_t<4,1><<<(NROW_/256)*(HID_/256), 512, 0, stream>>>(hb, wqT, qfb, nullptr,
        nullptr, nullptr, nullptr, nullptr, NROW_, HID_, HID_, HID_/256);
    gemm_t<2,2><<<(NROW_/256)*(NKV_/128), 512, 0, stream>>>(hb, wkvT, kr, vt,
        knw, cosT, sinT, pids, NROW_, NKV_, HID_, NKV_/128);

    // 3. attention (8 waves, 128 q-rows/block, fused Q LN+RoPE)
    attn_fwd<<<B_*H_*(S_/128), 512, 0, stream>>>(qfb, kr, vt, qnw, cosT, sinT, pids, ao);

    // 4. output projection -> d_out (f32)
    gemm_t<4,0><<<(NROW_/256)*(HID_/256), 512, 0, stream>>>(ao, woT, out, nullptr,
        nullptr, nullptr, nullptr, nullptr, NROW_, HID_, H_*D_, HID_/256);
}

// Round 17
// 463.342 us; speedup vs baseline: 1.0897x; 1.0595x over previous
//
#include <hip/hip_runtime.h>
#include <hip/hip_bf16.h>
#include <cstdio>
#include <cstdint>

#define B_    2
#define S_    2048
#define H_    32
#define KVH_  8
#define D_    128
#define HID_  4096
#define WIN_  512
#define NROW_ (B_*S_)          // 4096 rows for projection GEMMs
#define NKV_  2048             // fused k|v output width
#define SCALE_ 0.08838834764831845f          // 128^-0.5
#define SL2E_  0.12751744932973953f          // SCALE_ * log2(e)

typedef __attribute__((ext_vector_type(8))) __bf16 bf16x8;
typedef __attribute__((ext_vector_type(4))) __bf16 bf16x4;
typedef __attribute__((ext_vector_type(4))) float  f32x4;

#define GAS __attribute__((address_space(1)))
#define LAS __attribute__((address_space(3)))

// ------------------------------------------------- merged prep: cvt hidden + 4 weight transposes
__global__ __launch_bounds__(256) void prep_all(const float* __restrict__ hidden,
                                                const float* __restrict__ wq,
                                                const float* __restrict__ wk,
                                                const float* __restrict__ wv,
                                                const float* __restrict__ wo,
                                                __hip_bfloat16* __restrict__ hb,
                                                __hip_bfloat16* __restrict__ wqT,
                                                __hip_bfloat16* __restrict__ wkvT,
                                                __hip_bfloat16* __restrict__ woT) {
    __shared__ float t[32][33];
    const int bid = blockIdx.x;
    if (bid < 16384) {
        const int i = (bid * 256 + threadIdx.x) * 4;
        float4 v = *(const float4*)(hidden + i);
        __hip_bfloat162 a, b;
        a.x = __float2bfloat16(v.x); a.y = __float2bfloat16(v.y);
        b.x = __float2bfloat16(v.z); b.y = __float2bfloat16(v.w);
        *(__hip_bfloat162*)(hb + i)     = a;
        *(__hip_bfloat162*)(hb + i + 2) = b;
        return;
    }
    const int tx = threadIdx.x & 31, ty = threadIdx.x >> 5;
    const int id = bid - 16384;
    const float* src; __hip_bfloat16* dst; int C, idx;   // R always 4096
    if (id < 16384)      { src = wq; dst = wqT;  C = 4096; idx = id; }
    else if (id < 20480) { src = wk; dst = wkvT; C = 1024; idx = id - 16384; }
    else if (id < 24576) { src = wv; dst = wkvT + (size_t)1024*HID_; C = 1024; idx = id - 20480; }
    else                 { src = wo; dst = woT;  C = 4096; idx = id - 24576; }
    const int ctiles = C >> 5;
    const int c0 = (idx % ctiles) * 32, r0 = (idx / ctiles) * 32;
    #pragma unroll
    for (int i = 0; i < 4; ++i)
        t[ty + 8*i][tx] = src[(size_t)(r0 + ty + 8*i) * C + c0 + tx];
    __syncthreads();
    #pragma unroll
    for (int i = 0; i < 4; ++i)
        dst[(size_t)(c0 + ty + 8*i) * HID_ + r0 + tx] = __float2bfloat16(t[tx][ty + 8*i]);
}

// ------------------------------------------------- GEMM 256xBN, BK=32, ring-4, 1-barrier/tile
// R10-proven schedule (session best).  OMODE 0: f32 out.  1: bf16 out.  2: KV split —
// bx<8: K cols bf16 flat (LD 1024); bx>=8: V cols transposed via LDS into C2 = vt.
template <int FN, int OMODE>
__global__ __launch_bounds__(512, 2) void gemm_t(const __hip_bfloat16* __restrict__ A,
                                                 const __hip_bfloat16* __restrict__ Bt,
                                                 void* __restrict__ Cv, void* __restrict__ C2,
                                                 int M, int N, int K, int nbx) {
    constexpr int BN   = FN * 64;
    constexpr int BLD  = BN / 128;                      // B stage loads/thread/tile (2 or 1)
    constexpr int SLOT = (256 + BN) * 32;               // elems per ring slot (A then B)
    __shared__ __align__(16) __hip_bfloat16 L[4 * SLOT];
    const int tid  = threadIdx.x;
    const int lane = tid & 63, w = tid >> 6;
    const int wm = w >> 2, wn = w & 3;                  // 2 x 4 wave grid
    const int lc = lane & 15, lg = lane >> 4;
    const int nwg = gridDim.x, cpx = nwg >> 3;
    const int bid = blockIdx.x;
    const int swz = (bid & 7) * cpx + (bid >> 3);
    const int by = swz / nbx, bx = swz - by * nbx;
    const size_t row0 = (size_t)by * 256, col0 = (size_t)bx * BN;
    const int nt = K >> 5;                              // BK = 32

    const int srow = tid >> 2;
    const int spc  = tid & 3;
    const int slx  = spc ^ ((srow >> 1) & 3);
    const __hip_bfloat16* Ab = A  + row0 * K;
    const __hip_bfloat16* Bb = Bt + col0 * K;

#define STGA(tile_) do {                                                                   \
    const int ss_ = (tile_) & 3;                                                           \
    const int kt_ = ((tile_) < nt) ? (tile_) : (nt - 1);                                   \
    _Pragma("unroll")                                                                      \
    for (int rh_ = 0; rh_ < 2; ++rh_)                                                      \
        __builtin_amdgcn_global_load_lds(                                                  \
            (const GAS void*)(Ab + (size_t)(rh_*128 + srow) * K + kt_*32 + slx*8),         \
            (LAS void*)&L[ss_*SLOT + rh_*4096 + w*512], 16, 0, 0);                         \
} while (0)

#define STGB(tile_) do {                                                                   \
    const int ss_ = (tile_) & 3;                                                           \
    const int kt_ = ((tile_) < nt) ? (tile_) : (nt - 1);                                   \
    _Pragma("unroll")                                                                      \
    for (int bh_ = 0; bh_ < BLD; ++bh_)                                                    \
        __builtin_amdgcn_global_load_lds(                                                  \
            (const GAS void*)(Bb + (size_t)(bh_*128 + srow) * K + kt_*32 + slx*8),         \
            (LAS void*)&L[ss_*SLOT + 8192 + bh_*4096 + w*512], 16, 0, 0);                  \
} while (0)

#define VMW2L() do {                                                                       \
    if constexpr (FN == 4) asm volatile("s_waitcnt vmcnt(8)" ::: "memory");                \
    else                   asm volatile("s_waitcnt vmcnt(6)" ::: "memory");                \
} while (0)

    f32x4 acc[2][4][FN] = {};
    bf16x8 afr0[4], afr1[4], bfr[FN];

    STGA(0); STGB(0); STGA(1); STGB(1); STGA(2); STGB(2);
    VMW2L();
    asm volatile("s_barrier" ::: "memory");

    for (int t = 0; t < nt; ++t) {
        const int s_ = t & 3;
        #pragma unroll
        for (int fn = 0; fn < FN; ++fn) {
            const int rB = wn*(FN*16) + fn*16 + lc;
            bfr[fn] = *(const bf16x8*)&L[s_*SLOT + 8192 + rB*32 + ((lg ^ ((rB >> 1) & 3)) * 8)];
        }
        #pragma unroll
        for (int fm = 0; fm < 4; ++fm) {
            const int rA = wm*128 + fm*16 + lc;
            afr0[fm] = *(const bf16x8*)&L[s_*SLOT + rA*32 + ((lg ^ ((rA >> 1) & 3)) * 8)];
        }
        __builtin_amdgcn_sched_barrier(0);              // pin group order for counted lgkm
        #pragma unroll
        for (int fm = 0; fm < 4; ++fm) {
            const int rA = wm*128 + 64 + fm*16 + lc;
            afr1[fm] = *(const bf16x8*)&L[s_*SLOT + rA*32 + ((lg ^ ((rA >> 1) & 3)) * 8)];
        }
        STGA(t + 3);
        asm volatile("s_waitcnt lgkmcnt(4)" ::: "memory");   // group 1 done; group 2 in flight
        __builtin_amdgcn_sched_barrier(0);
        __builtin_amdgcn_s_setprio(1);
        #pragma unroll
        for (int fm = 0; fm < 4; ++fm)
            #pragma unroll
            for (int fn = 0; fn < FN; ++fn)
                acc[0][fm][fn] = __builtin_amdgcn_mfma_f32_16x16x32_bf16(
                    afr0[fm], bfr[fn], acc[0][fm][fn], 0, 0, 0);
        __builtin_amdgcn_s_setprio(0);

        STGB(t + 3);
        asm volatile("s_waitcnt lgkmcnt(0)" ::: "memory");   // group 2 drained under alpha
        __builtin_amdgcn_sched_barrier(0);
        __builtin_amdgcn_s_setprio(1);
        #pragma unroll
        for (int fm = 0; fm < 4; ++fm)
            #pragma unroll
            for (int fn = 0; fn < FN; ++fn)
                acc[1][fm][fn] = __builtin_amdgcn_mfma_f32_16x16x32_bf16(
                    afr1[fm], bfr[fn], acc[1][fm][fn], 0, 0, 0);
        __builtin_amdgcn_s_setprio(0);
        VMW2L();                                        // tile t+1 fully landed (2L outstanding)
        asm volatile("s_barrier" ::: "memory");         // ... before tile t+1's reads
    }
#undef STGA
#undef STGB
#undef VMW2L
    asm volatile("s_waitcnt vmcnt(0)" ::: "memory");    // drain clamped tail stages

    if constexpr (OMODE == 0) {
        float* C = (float*)Cv;
        #pragma unroll
        for (int qm = 0; qm < 2; ++qm)
            #pragma unroll
            for (int fm = 0; fm < 4; ++fm)
                #pragma unroll
                for (int fn = 0; fn < FN; ++fn) {
                    const size_t col = col0 + wn*(FN*16) + fn*16 + lc;
                    #pragma unroll
                    for (int rr = 0; rr < 4; ++rr) {
                        const size_t row = row0 + wm*128 + qm*64 + fm*16 + lg*4 + rr;
                        C[row * N + col] = acc[qm][fm][fn][rr];
                    }
                }
    } else if constexpr (OMODE == 1) {
        __hip_bfloat16* C = (__hip_bfloat16*)Cv;
        #pragma unroll
        for (int qm = 0; qm < 2; ++qm)
            #pragma unroll
            for (int fm = 0; fm < 4; ++fm)
                #pragma unroll
                for (int fn = 0; fn < FN; ++fn) {
                    const size_t col = col0 + wn*(FN*16) + fn*16 + lc;
                    #pragma unroll
                    for (int rr = 0; rr < 4; ++rr) {
                        const size_t row = row0 + wm*128 + qm*64 + fm*16 + lg*4 + rr;
                        C[row * N + col] = __float2bfloat16(acc[qm][fm][fn][rr]);
                    }
                }
    } else {                                            // OMODE 2: KV split (FN==2, BN=128)
        if (bx < 8) {                                   // K columns -> kf bf16, LD 1024
            __hip_bfloat16* C = (__hip_bfloat16*)Cv;
            #pragma unroll
            for (int qm = 0; qm < 2; ++qm)
                #pragma unroll
                for (int fm = 0; fm < 4; ++fm)
                    #pragma unroll
                    for (int fn = 0; fn < FN; ++fn) {
                        const size_t col = col0 + wn*32 + fn*16 + lc;
                        #pragma unroll
                        for (int rr = 0; rr < 4; ++rr) {
                            const size_t row = row0 + wm*128 + qm*64 + fm*16 + lg*4 + rr;
                            C[row * 1024 + col] = __float2bfloat16(acc[qm][fm][fn][rr]);
                        }
                    }
        } else {                                        // V columns -> vt (B,KVH,D,S) via LDS
            __hip_bfloat16* lt = (__hip_bfloat16*)L;    // [128 d][264 pad]
            __syncthreads();
            #pragma unroll
            for (int qm = 0; qm < 2; ++qm)
                #pragma unroll
                for (int fm = 0; fm < 4; ++fm)
                    #pragma unroll
                    for (int fn = 0; fn < FN; ++fn) {
                        const int cl = wn*32 + fn*16 + lc;
                        #pragma unroll
                        for (int rr = 0; rr < 4; ++rr) {
                            const int rl = wm*128 + qm*64 + fm*16 + lg*4 + rr;
                            lt[cl*264 + rl] = __float2bfloat16(acc[qm][fm][fn][rr]);
                        }
                    }
            __syncthreads();
            const int bb = (int)(row0 >> 11), s0 = (int)(row0 & 2047);
            const int g  = (int)((col0 - 1024) >> 7);
            __hip_bfloat16* vto = (__hip_bfloat16*)C2 + (((size_t)bb*KVH_ + g) * D_) * (size_t)S_;
            const int d = tid >> 2, sc0 = (tid & 3) * 64;
            #pragma unroll
            for (int j = 0; j < 64; j += 8) {
                bf16x8 v = *(const bf16x8*)&lt[d*264 + sc0 + j];
                *(bf16x8*)&vto[(size_t)d*S_ + s0 + sc0 + j] = v;
            }
        }
    }
}

// ------------------------------------------------- per-head LN + interleaved RoPE (bf16 in)
// used only for K.  in: x (B*S, LD) bf16.  out: (B, NH, S, D) bf16.
template <int NH, int LD, int XOFF>
__global__ __launch_bounds__(256) void ln_rope(const __hip_bfloat16* __restrict__ x,
                                               const float* __restrict__ wln,
                                               const float* __restrict__ cosT,
                                               const float* __restrict__ sinT,
                                               const int* __restrict__ pids,
                                               __hip_bfloat16* __restrict__ out) {
    const int lane = threadIdx.x & 63, wv = threadIdx.x >> 6;
    const int r = blockIdx.x * 4 + wv;
    const int h = r % NH;
    const int bs = r / NH;
    const int b = bs / S_, s = bs % S_;
    const __hip_bfloat162 xv2 = *(const __hip_bfloat162*)(x + (size_t)bs * LD + XOFF + h*D_ + lane*2);
    const float x0 = __bfloat162float(xv2.x), x1 = __bfloat162float(xv2.y);
    float sum = x0 + x1;
    #pragma unroll
    for (int o = 32; o; o >>= 1) sum += __shfl_xor(sum, o);
    const float mu = sum * (1.f / D_);
    const float dx = x0 - mu, dy = x1 - mu;
    float vs = dx*dx + dy*dy;
    #pragma unroll
    for (int o = 32; o; o >>= 1) vs += __shfl_xor(vs, o);
    const float rs = rsqrtf(vs * (1.f / D_) + 1e-5f);
    const float2 w2 = *(const float2*)(wln + lane*2);
    const float y0 = w2.x * dx * rs, y1 = w2.y * dy * rs;
    const int p = pids[bs];
    const float2 c  = *(const float2*)(cosT + (size_t)p * D_ + lane*2);
    const float2 sn = *(const float2*)(sinT + (size_t)p * D_ + lane*2);
    __hip_bfloat162 ov;
    ov.x = __float2bfloat16(y0 * c.x - y1 * sn.x);
    ov.y = __float2bfloat16(y1 * c.y + y0 * sn.y);
    *(__hip_bfloat162*)(out + (((size_t)b * NH + h) * S_ + s) * D_ + lane*2) = ov;
}

// chunk swizzle for K tile (16B chunks, 16/row)
static __device__ __forceinline__ int sigk_(int r) { return (r & 3) | ((r >> 1) & 4); }

// ------------------------------------------------- sliding-window GQA flash attention v4
// 8 waves / 128 q-rows per block (2 blocks/CU -> 4 waves/SIMD TLP); Q LayerNorm+RoPE fused
// in-register (reads qfb directly); swapped QK^T; K/V^T LDS-staged via global_load_lds,
// double-buffered, counted vmcnt(4) + raw s_barrier.
__global__ __launch_bounds__(512, 4) void attn_fwd(const __hip_bfloat16* __restrict__ qfb,
                                                   const __hip_bfloat16* __restrict__ kr,
                                                   const __hip_bfloat16* __restrict__ vt,
                                                   const float* __restrict__ qnw,
                                                   const float* __restrict__ cosT,
                                                   const float* __restrict__ sinT,
                                                   const int* __restrict__ pids,
                                                   __hip_bfloat16* __restrict__ ao) {
    __shared__ __align__(16) __hip_bfloat16 Ksl[2][64*D_];    // 2 x 16KB
    __shared__ __align__(16) __hip_bfloat16 Vsl[2][D_*64];    // 2 x 16KB
    const int tid = threadIdx.x;
    const int lane = tid & 63, w = tid >> 6;     // 8 waves
    const int lq = lane & 15, lg = lane >> 4;
    const int blk = blockIdx.x;
    const int qt = blk & 15;
    const int bh = blk >> 4;
    const int h = bh & (H_-1), b = bh >> 5;
    const int g = h >> 2;
    const int q0 = qt*128 + w*16;
    const int q  = q0 + lq;

    const __hip_bfloat16* kbase = kr + ((size_t)b*KVH_ + g) * (size_t)S_ * D_;
    const __hip_bfloat16* vbase = vt + ((size_t)b*KVH_ + g) * (size_t)D_ * S_;

    const int srK = lane >> 4, scK = lane & 15;
    const int srV = lane >> 3, scV = lane & 7;

#define STAGE(nb, k0s) do {                                                              \
    _Pragma("unroll")                                                                    \
    for (int s_ = 0; s_ < 2; ++s_) {                                                     \
        const int rK_ = w*8 + s_*4 + srK;                                                \
        const __hip_bfloat16* srcK_ = kbase + (size_t)((k0s) + rK_)*D_                   \
                                      + ((scK ^ sigk_(rK_)) * 8);                        \
        __builtin_amdgcn_global_load_lds((const GAS void*)srcK_,                         \
            (LAS void*)&Ksl[nb][(w*8 + s_*4)*D_], 16, 0, 0);                             \
    }                                                                                    \
    _Pragma("unroll")                                                                    \
    for (int s_ = 0; s_ < 2; ++s_) {                                                     \
        const int dV_ = w*16 + s_*8 + srV;                                               \
        const __hip_bfloat16* srcV_ = vbase + (size_t)dV_*S_ + (k0s)                     \
                                      + ((scV ^ (dV_ & 7)) * 8);                         \
        __builtin_amdgcn_global_load_lds((const GAS void*)srcV_,                         \
            (LAS void*)&Vsl[nb][(w*16 + s_*8)*64], 16, 0, 0);                            \
    }                                                                                    \
} while (0)

    int kst = qt*128 - (WIN_ - 1); if (kst < 0) kst = 0; kst &= ~63;
    const int nt = qt*2 + 2 - (kst >> 6);

    union { bf16x8 v; __hip_bfloat16 e[8]; } qraw[4];
    const __hip_bfloat16* qb2 = qfb + ((size_t)(b*S_ + q)) * HID_ + h*D_;
    #pragma unroll
    for (int kk = 0; kk < 4; ++kk)
        qraw[kk].v = *(const bf16x8*)(qb2 + kk*32 + lg*8);
    const int p = pids[b*S_ + q];

    STAGE(0, kst);

    float sum = 0.f;
    #pragma unroll
    for (int kk = 0; kk < 4; ++kk)
        #pragma unroll
        for (int j = 0; j < 8; ++j) sum += __bfloat162float(qraw[kk].e[j]);
    sum += __shfl_xor(sum, 16); sum += __shfl_xor(sum, 32);
    const float mu = sum * (1.f / D_);
    float vsq = 0.f;
    #pragma unroll
    for (int kk = 0; kk < 4; ++kk)
        #pragma unroll
        for (int j = 0; j < 8; ++j) {
            const float dxx = __bfloat162float(qraw[kk].e[j]) - mu;
            vsq += dxx * dxx;
        }
    vsq += __shfl_xor(vsq, 16); vsq += __shfl_xor(vsq, 32);
    const float rsq = rsqrtf(vsq * (1.f / D_) + 1e-5f);

    bf16x8 qf[4];
    #pragma unroll
    for (int kk = 0; kk < 4; ++kk) {
        const int d0 = kk*32 + lg*8;
        float wl[8], cc[8], ss[8], y[8];
        *(float4*)&wl[0] = *(const float4*)(qnw + d0);
        *(float4*)&wl[4] = *(const float4*)(qnw + d0 + 4);
        *(float4*)&cc[0] = *(const float4*)(cosT + (size_t)p*D_ + d0);
        *(float4*)&cc[4] = *(const float4*)(cosT + (size_t)p*D_ + d0 + 4);
        *(float4*)&ss[0] = *(const float4*)(sinT + (size_t)p*D_ + d0);
        *(float4*)&ss[4] = *(const float4*)(sinT + (size_t)p*D_ + d0 + 4);
        #pragma unroll
        for (int j = 0; j < 8; ++j)
            y[j] = wl[j] * (__bfloat162float(qraw[kk].e[j]) - mu) * rsq;
        union { bf16x8 v; __hip_bfloat16 e[8]; } qo;
        #pragma unroll
        for (int mpair = 0; mpair < 4; ++mpair) {
            qo.e[2*mpair]   = __float2bfloat16(y[2*mpair]   * cc[2*mpair]   - y[2*mpair+1] * ss[2*mpair]);
            qo.e[2*mpair+1] = __float2bfloat16(y[2*mpair+1] * cc[2*mpair+1] + y[2*mpair]   * ss[2*mpair+1]);
        }
        qf[kk] = qo.v;
    }

    f32x4 o[8] = {};
    float m = -1e30f, l = 0.f;
    const int kldrow = 8*(lq >> 2) + (lq & 3);

    for (int t = 0; t < nt; ++t) {
        const int k0 = kst + t*64;
        const int buf = t & 1;
        if (t + 1 < nt) {
            STAGE((t + 1) & 1, k0 + 64);
            asm volatile("s_waitcnt vmcnt(4)" ::: "memory");
        } else {
            asm volatile("s_waitcnt vmcnt(0)" ::: "memory");
        }
        __builtin_amdgcn_s_barrier();

        f32x4 sc[2][2] = {};
        __builtin_amdgcn_s_setprio(1);
        #pragma unroll
        for (int kb = 0; kb < 2; ++kb)
            #pragma unroll
            for (int f = 0; f < 2; ++f) {
                const int rA = kb*32 + 4*f + kldrow;
                const __hip_bfloat16* kp = &Ksl[buf][rA*D_];
                #pragma unroll
                for (int kk = 0; kk < 4; ++kk) {
                    bf16x8 ka = *(const bf16x8*)(kp + (((kk*4 + lg) ^ sigk_(rA)) * 8));
                    sc[kb][f] = __builtin_amdgcn_mfma_f32_16x16x32_bf16(ka, qf[kk], sc[kb][f], 0, 0, 0);
                }
            }
        __builtin_amdgcn_s_setprio(0);

        const int dqk = q - (k0 + 8*lg);
        float pv[16];
        float mx = -INFINITY;
        #pragma unroll
        for (int kb = 0; kb < 2; ++kb)
            #pragma unroll
            for (int f = 0; f < 2; ++f)
                #pragma unroll
                for (int r = 0; r < 4; ++r) {
                    const int c = kb*32 + 4*f + r;
                    const int d = dqk - c;
                    float v = (d >= 0 && d < WIN_) ? sc[kb][f][r] * SL2E_ : -INFINITY;
                    pv[kb*8 + f*4 + r] = v;
                    mx = fmaxf(mx, v);
                }
        mx = fmaxf(mx, __shfl_xor(mx, 16));
        mx = fmaxf(mx, __shfl_xor(mx, 32));
        const float mn = fmaxf(m, mx);
        const float alpha = exp2f(m - mn);
        float ls = 0.f;
        union { bf16x8 v; __hip_bfloat16 e[8]; } pu[2];
        #pragma unroll
        for (int kb = 0; kb < 2; ++kb)
            #pragma unroll
            for (int j = 0; j < 8; ++j) {
                const float pw = exp2f(pv[kb*8 + j] - mn);
                ls += pw;
                pu[kb].e[j] = __float2bfloat16(pw);
            }
        ls += __shfl_xor(ls, 16);
        ls += __shfl_xor(ls, 32);
        l = l * alpha + ls;
        m = mn;
        #pragma unroll
        for (int n = 0; n < 8; ++n) {
            o[n][0] *= alpha; o[n][1] *= alpha; o[n][2] *= alpha; o[n][3] *= alpha;
        }

        __builtin_amdgcn_s_setprio(1);
        #pragma unroll
        for (int kb = 0; kb < 2; ++kb)
            #pragma unroll
            for (int n = 0; n < 8; ++n) {
                const int dR = n*16 + lq;
                bf16x8 vf8 = *(const bf16x8*)(&Vsl[buf][dR*64] + (((kb*4 + lg) ^ (dR & 7)) * 8));
                o[n] = __builtin_amdgcn_mfma_f32_16x16x32_bf16(vf8, pu[kb].v, o[n], 0, 0, 0);
            }
        __builtin_amdgcn_s_setprio(0);

        if (t + 1 < nt) __builtin_amdgcn_s_barrier();
    }
#undef STAGE

    const float rinv = 1.f / l;
    #pragma unroll
    for (int n = 0; n < 8; ++n) {
        union { bf16x4 v; __hip_bfloat16 e[4]; } ov;
        #pragma unroll
        for (int r = 0; r < 4; ++r) ov.e[r] = __float2bfloat16(o[n][r] * rinv);
        *(bf16x4*)(ao + ((size_t)b*S_ + q)*(H_*D_) + h*D_ + n*16 + lg*4) = ov.v;
    }
}

// ----------------------------------------------------------------- host
extern "C" void kernel_launch(void* const* d_in, const int* in_sizes, int n_in,
                              void* d_out, int out_size, void* d_ws, size_t ws_size,
                              hipStream_t stream) {
    const float* hidden = (const float*)d_in[0];
    const int*   pids   = (const int*)  d_in[1];
    const float* cosT   = (const float*)d_in[2];
    const float* sinT   = (const float*)d_in[3];
    const float* wq     = (const float*)d_in[4];
    const float* wk     = (const float*)d_in[5];
    const float* wv     = (const float*)d_in[6];
    const float* wo     = (const float*)d_in[7];
    const float* qnw    = (const float*)d_in[8];
    const float* knw    = (const float*)d_in[9];
    float* out = (float*)d_out;

    char* base = (char*)d_ws;
    size_t off = 0;
    auto take = [&](size_t bytes) -> void* {
        void* q = base + off;
        off = (off + bytes + 255) & ~(size_t)255;
        return q;
    };
    __hip_bfloat16* qfb  = (__hip_bfloat16*)take((size_t)NROW_*HID_*2);   // Q proj bf16
    __hip_bfloat16* ao   = (__hip_bfloat16*)take((size_t)NROW_*HID_*2);   // attn out bf16
    __hip_bfloat16* kf   = (__hip_bfloat16*)take((size_t)NROW_*1024*2);   // K proj bf16
    __hip_bfloat16* hb   = (__hip_bfloat16*)take((size_t)NROW_*HID_*2);
    __hip_bfloat16* wqT  = (__hip_bfloat16*)take((size_t)HID_*HID_*2);
    __hip_bfloat16* wkvT = (__hip_bfloat16*)take((size_t)NKV_*HID_*2);
    __hip_bfloat16* woT  = (__hip_bfloat16*)take((size_t)HID_*HID_*2);
    __hip_bfloat16* kr   = (__hip_bfloat16*)take((size_t)B_*KVH_*S_*D_*2);
    __hip_bfloat16* vt   = (__hip_bfloat16*)take((size_t)B_*KVH_*S_*D_*2);

    if (off > ws_size) {
        fprintf(stderr, "WORKSPACE TOO SMALL: need %zu have %zu\n", off, ws_size);
        return;
    }

    // 1. merged prep: hidden convert + 4 weight transposes (1 launch)
    prep_all<<<16384 + 40960, 256, 0, stream>>>(hidden, wq, wk, wv, wo, hb, wqT, wkvT, woT);

    // 2. projections — every grid exactly 256 blocks (1 round on 256 CUs)
    gemm_t<4,1><<<(NROW_/256)*(HID_/256), 512, 0, stream>>>(hb, wqT,  qfb, nullptr, NROW_, HID_, HID_, HID_/256);
    gemm_t<2,2><<<(NROW_/256)*(NKV_/128), 512, 0, stream>>>(hb, wkvT, kf,  vt,      NROW_, NKV_, HID_, NKV_/128);

    // 3. LN + RoPE for K only (Q is fused into attention)
    ln_rope<KVH_, 1024, 0><<<(B_*S_*KVH_)/4, 256, 0, stream>>>(kf, knw, cosT, sinT, pids, kr);

    // 4. attention (8 waves, 128 q-rows/block, fused Q LN+RoPE)
    attn_fwd<<<B_*H_*(S_/128), 512, 0, stream>>>(qfb, kr, vt, qnw, cosT, sinT, pids, ao);

    // 5. output projection -> d_out (f32)
    gemm_t<4,0><<<(NROW_/256)*(HID_/256), 512, 0, stream>>>(ao, woT, out, nullptr, NROW_, HID_, H_*D_, HID_/256);
}